// Round 8
// baseline (231.562 us; speedup 1.0000x reference)
//
#include <hip/hip_runtime.h>
#include <hip/hip_bf16.h>
#include <math.h>

typedef __attribute__((ext_vector_type(8))) short bf16x8;
typedef __attribute__((ext_vector_type(16))) float f32x16;

#define B_ 2
#define L_ 2048
#define S_ 2048
#define H_ 16
#define E_ 64
#define D_ 64

#define EXP2(x) exp2f(x)

__device__ __forceinline__ unsigned pkbf(float a, float b) {
  __hip_bfloat162 h = __float22bfloat162_rn(float2{a, b});
  return *(unsigned*)&h;
}

// D-frag row for mfma_f32_32x32x16: row = (r&3) + 8*(r>>2) + 4*hi5
__device__ __forceinline__ int crow(int r, int hi5) {
  return (r & 3) + ((r >> 2) << 3) + (hi5 << 2);
}

__global__ __launch_bounds__(512, 4)
void fa_fwd6(const float* __restrict__ Qp, const float* __restrict__ Kp,
             const float* __restrict__ Vp, float* __restrict__ Op) {
  // 4 slots: [half*2 + buf], each 16KB = K tile (8KB) | V^T tile (8KB)
  __shared__ uint4 sbuf[4][1024];

  const int tid  = threadIdx.x;
  const int lane = tid & 63;
  const int w    = tid >> 6;      // 8 waves
  const int half = w >> 2;        // KV half this wave works on
  const int wq   = w & 3;         // q-subtile (32 rows)
  const int l31  = lane & 31;
  const int hi5  = lane >> 5;

  // pairing: blocks B and B+256 share bh and get qidx (8+r, 7-r) ->
  // per-CU round total constant (confirmed by round-7 occupancy ~ model)
  const int Bx   = blockIdx.x;
  const int r_   = (Bx >> 5) & 7;
  const int bh   = Bx & 31;
  const int b    = bh >> 4, h = bh & 15;
  const int qidx = (Bx >> 8) ? (7 - r_) : (8 + r_);
  const int q0   = qidx << 7;         // 128-row q block
  const int qw   = q0 + wq * 32;      // this wave's 32 q-rows
  const int R    = qidx + 1;          // rounds = kv tiles per half
  const int tb   = half * R;          // my half's first tile index

  const float cs = 0.125f * 1.44269504088896f;  // 1/sqrt(E) * log2(e)

  // staging coords within this half's 256-thread group
  const int st   = tid & 255;
  const int krow = st >> 2, ksg = st & 3;     // K: 64 rows x 4 segs
  const int vd   = st & 63, kg  = st >> 6;    // V: 64 d-cols x 4 kv-groups
  const int kswz = (krow & 7) << 4;
  const int vswz = (vd & 7) << 4;

  // ---- Q fragments (B-operand of swapped QK^T), pre-scaled, in regs ----
  bf16x8 qf[4];
  {
    const int qg = qw + l31;
    const float* gq = Qp + ((size_t)(b * L_ + qg) * H_ + h) * E_ + hi5 * 8;
    #pragma unroll
    for (int ec = 0; ec < 4; ++ec) {
      float4 a = *(const float4*)(gq + ec * 16);
      float4 c = *(const float4*)(gq + ec * 16 + 4);
      uint4 u;
      u.x = pkbf(a.x * cs, a.y * cs);
      u.y = pkbf(a.z * cs, a.w * cs);
      u.z = pkbf(c.x * cs, c.y * cs);
      u.w = pkbf(c.z * cs, c.w * cs);
      qf[ec] = *(bf16x8*)&u;
    }
  }

  f32x16 acc[2];
  #pragma unroll
  for (int dt = 0; dt < 2; ++dt)
    #pragma unroll
    for (int rr = 0; rr < 16; ++rr) acc[dt][rr] = 0.f;

  float mrun = -INFINITY;
  float lsum = 0.f;

  // ---- prologue: stage my half's tile tb into slot[half*2 + 0] ----
  {
    char* lk = (char*)&sbuf[half * 2][0];
    char* lv = lk + 8192;
    const int kv0 = tb * 64;
    const float* gk = Kp + ((size_t)(b * S_ + kv0 + krow) * H_ + h) * E_ + ksg * 8;
    #pragma unroll
    for (int j = 0; j < 2; ++j) {
      float4 a = *(const float4*)(gk + j * 32);
      float4 c = *(const float4*)(gk + j * 32 + 4);
      uint4 u;
      u.x = pkbf(a.x, a.y); u.y = pkbf(a.z, a.w);
      u.z = pkbf(c.x, c.y); u.w = pkbf(c.z, c.w);
      *(uint4*)(lk + ((krow * 128 + ksg * 16 + j * 64) ^ kswz)) = u;
    }
    #pragma unroll
    for (int j = 0; j < 2; ++j) {
      const float* gv = Vp + ((size_t)(b * S_ + kv0 + kg * 16 + j * 8) * H_ + h) * D_ + vd;
      float v0 = gv[(size_t)0 * (H_ * D_)];
      float v1 = gv[(size_t)1 * (H_ * D_)];
      float v2 = gv[(size_t)2 * (H_ * D_)];
      float v3 = gv[(size_t)3 * (H_ * D_)];
      float v4 = gv[(size_t)4 * (H_ * D_)];
      float v5 = gv[(size_t)5 * (H_ * D_)];
      float v6 = gv[(size_t)6 * (H_ * D_)];
      float v7 = gv[(size_t)7 * (H_ * D_)];
      uint4 u;
      u.x = pkbf(v0, v1); u.y = pkbf(v2, v3);
      u.z = pkbf(v4, v5); u.w = pkbf(v6, v7);
      *(uint4*)(lv + ((vd * 128 + kg * 32 + j * 16) ^ vswz)) = u;
    }
  }
  __syncthreads();

  int cur = 0;
  for (int rho = 0; rho < R; ++rho, cur ^= 1) {
    const int tau = tb + rho;
    const int kv0 = tau * 64;
    const bool have_next = (rho + 1) < R;

    // ---- issue next-round global loads EARLY (in flight during compute) ----
    float4 Ka[2], Kc[2];
    float Vv[16];
    if (have_next) {
      const int kvn = kv0 + 64;
      const float* gk = Kp + ((size_t)(b * S_ + kvn + krow) * H_ + h) * E_ + ksg * 8;
      Ka[0] = *(const float4*)(gk);
      Kc[0] = *(const float4*)(gk + 4);
      Ka[1] = *(const float4*)(gk + 32);
      Kc[1] = *(const float4*)(gk + 36);
      #pragma unroll
      for (int j = 0; j < 2; ++j) {
        const float* gv = Vp + ((size_t)(b * S_ + kvn + kg * 16 + j * 8) * H_ + h) * D_ + vd;
        #pragma unroll
        for (int k2 = 0; k2 < 8; ++k2)
          Vv[j * 8 + k2] = gv[(size_t)k2 * (H_ * D_)];
      }
    }

    // ---- compute on slot[half*2 + cur] ----
    if (kv0 <= qw + 31) {        // (only half1's last round can skip, subs 0/1)
      char* lk = (char*)&sbuf[half * 2 + cur][0];
      char* lv = lk + 8192;
      const bool needmask = (kv0 + 63) > qw;

      f32x16 stt[2];
      #pragma unroll
      for (int c = 0; c < 2; ++c)
        #pragma unroll
        for (int rr = 0; rr < 16; ++rr) stt[c][rr] = 0.f;
      __builtin_amdgcn_s_setprio(1);
      #pragma unroll
      for (int c = 0; c < 2; ++c) {
        const int row = c * 32 + l31;
        const int sw = (row & 7) << 4;
        #pragma unroll
        for (int ec = 0; ec < 4; ++ec) {
          bf16x8 kf = *(bf16x8*)(lk + ((row * 128 + ec * 32 + hi5 * 16) ^ sw));
          stt[c] = __builtin_amdgcn_mfma_f32_32x32x16_bf16(kf, qf[ec], stt[c], 0, 0, 0);
        }
      }
      __builtin_amdgcn_s_setprio(0);

      if (needmask) {
        const int qg = qw + l31;
        #pragma unroll
        for (int c = 0; c < 2; ++c)
          #pragma unroll
          for (int rr = 0; rr < 16; ++rr)
            if (kv0 + c * 32 + crow(rr, hi5) > qg) stt[c][rr] = -1e30f;
      }

      // online softmax, defer-max (THR=8 in log2 domain)
      float pm = stt[0][0];
      #pragma unroll
      for (int c = 0; c < 2; ++c)
        #pragma unroll
        for (int rr = 0; rr < 16; ++rr) pm = fmaxf(pm, stt[c][rr]);
      pm = fmaxf(pm, __shfl_xor(pm, 32));

      if (__any(pm > mrun + 8.f)) {
        const float mn = fmaxf(mrun, pm);
        const float f = EXP2(mrun - mn);
        mrun = mn;
        lsum *= f;
        #pragma unroll
        for (int rr = 0; rr < 16; ++rr) {
          const float fr = __shfl(f, crow(rr, hi5));
          acc[0][rr] *= fr;
          acc[1][rr] *= fr;
        }
      }
      {
        float ps = 0.f;
        #pragma unroll
        for (int c = 0; c < 2; ++c)
          #pragma unroll
          for (int rr = 0; rr < 16; ++rr) {
            stt[c][rr] = EXP2(stt[c][rr] - mrun);
            ps += stt[c][rr];
          }
        ps += __shfl_xor(ps, 32);
        lsum += ps;
      }

      // P -> PA fragments (pack pairs + lane^32 exchange)
      uint4 pa[4];
      #pragma unroll
      for (int c = 0; c < 2; ++c) {
        unsigned Dw[8];
        #pragma unroll
        for (int j = 0; j < 8; ++j)
          Dw[j] = pkbf(stt[c][2 * j], stt[c][2 * j + 1]);
        unsigned y0 = __shfl_xor((int)(hi5 ? Dw[0] : Dw[2]), 32);
        unsigned y1 = __shfl_xor((int)(hi5 ? Dw[1] : Dw[3]), 32);
        unsigned y2 = __shfl_xor((int)(hi5 ? Dw[4] : Dw[6]), 32);
        unsigned y3 = __shfl_xor((int)(hi5 ? Dw[5] : Dw[7]), 32);
        uint4 p0, p1;
        if (hi5) {
          p0 = uint4{y0, y1, Dw[2], Dw[3]};
          p1 = uint4{y2, y3, Dw[6], Dw[7]};
        } else {
          p0 = uint4{Dw[0], Dw[1], y0, y1};
          p1 = uint4{Dw[4], Dw[5], y2, y3};
        }
        pa[2 * c]     = p0;
        pa[2 * c + 1] = p1;
      }

      // PV: acc[dt] += P(32q x 16kv) . V(16kv x 32d)
      __builtin_amdgcn_s_setprio(1);
      #pragma unroll
      for (int s = 0; s < 4; ++s) {
        #pragma unroll
        for (int dt = 0; dt < 2; ++dt) {
          const int row = dt * 32 + l31;
          bf16x8 vf = *(bf16x8*)(lv + ((row * 128 + s * 32 + hi5 * 16) ^ ((row & 7) << 4)));
          acc[dt] = __builtin_amdgcn_mfma_f32_32x32x16_bf16(*(bf16x8*)&pa[s], vf, acc[dt], 0, 0, 0);
        }
      }
      __builtin_amdgcn_s_setprio(0);
    }

    // ---- write next tile into the other buffer (after compute) ----
    if (have_next) {
      char* lk = (char*)&sbuf[half * 2 + (cur ^ 1)][0];
      char* lv = lk + 8192;
      #pragma unroll
      for (int j = 0; j < 2; ++j) {
        uint4 u;
        u.x = pkbf(Ka[j].x, Ka[j].y); u.y = pkbf(Ka[j].z, Ka[j].w);
        u.z = pkbf(Kc[j].x, Kc[j].y); u.w = pkbf(Kc[j].z, Kc[j].w);
        *(uint4*)(lk + ((krow * 128 + ksg * 16 + j * 64) ^ kswz)) = u;
      }
      #pragma unroll
      for (int j = 0; j < 2; ++j) {
        uint4 u;
        u.x = pkbf(Vv[j * 8 + 0], Vv[j * 8 + 1]);
        u.y = pkbf(Vv[j * 8 + 2], Vv[j * 8 + 3]);
        u.z = pkbf(Vv[j * 8 + 4], Vv[j * 8 + 5]);
        u.w = pkbf(Vv[j * 8 + 6], Vv[j * 8 + 7]);
        *(uint4*)(lv + ((vd * 128 + kg * 32 + j * 16) ^ vswz)) = u;
      }
    }
    __syncthreads();
  }

  // ---- merge the two KV-half partials (LSE merge) + epilogue ----
  __syncthreads();   // make sbuf reusable as merge scratch
  char* mb = (char*)&sbuf[0][0];
  const int mswz = (lane & 7) << 4;
  if (half) {
    char* pa_ = mb + wq * 8192 + lane * 128;
    #pragma unroll
    for (int j = 0; j < 4; ++j) {
      *(uint4*)(pa_ + ((j * 16) ^ mswz))      = ((uint4*)&acc[0])[j];
      *(uint4*)(pa_ + ((64 + j * 16) ^ mswz)) = ((uint4*)&acc[1])[j];
    }
    *(float2*)(mb + 32768 + (wq * 64 + lane) * 8) = float2{mrun, lsum};
  }
  __syncthreads();
  if (!half) {
    char* pa_ = mb + wq * 8192 + lane * 128;
    f32x16 a1[2];
    #pragma unroll
    for (int j = 0; j < 4; ++j) {
      ((uint4*)&a1[0])[j] = *(uint4*)(pa_ + ((j * 16) ^ mswz));
      ((uint4*)&a1[1])[j] = *(uint4*)(pa_ + ((64 + j * 16) ^ mswz));
    }
    float2 ml = *(float2*)(mb + 32768 + (wq * 64 + lane) * 8);
    const float m1 = ml.x, l1 = ml.y;
    const float mm = fmaxf(mrun, m1);
    const float f0 = EXP2(mrun - mm);
    const float f1 = EXP2(m1 - mm);    // exp2(-inf)=0 covers empty half
    const float inv = 1.f / (lsum * f0 + l1 * f1);
    const float g0 = f0 * inv, g1 = f1 * inv;
    #pragma unroll
    for (int rr = 0; rr < 16; ++rr) {
      const int cr = crow(rr, hi5);
      const float w0 = __shfl(g0, cr);
      const float w1 = __shfl(g1, cr);
      const int qg = qw + cr;
      float* go = Op + ((size_t)(b * L_ + qg) * H_ + h) * D_ + l31;
      go[0]  = acc[0][rr] * w0 + a1[0][rr] * w1;
      go[32] = acc[1][rr] * w0 + a1[1][rr] * w1;
    }
  }
}

extern "C" void kernel_launch(void* const* d_in, const int* in_sizes, int n_in,
                              void* d_out, int out_size, void* d_ws, size_t ws_size,
                              hipStream_t stream) {
  (void)in_sizes; (void)n_in; (void)d_ws; (void)ws_size; (void)out_size;
  const float* Q = (const float*)d_in[0];
  const float* K = (const float*)d_in[1];
  const float* V = (const float*)d_in[2];
  float* O = (float*)d_out;
  fa_fwd6<<<dim3(512), dim3(512), 0, stream>>>(Q, K, V, O);
}

// Round 9
// 64.292 us; speedup vs baseline: 3.6017x; 3.6017x over previous
//
#include <hip/hip_runtime.h>
#include <hip/hip_bf16.h>
#include <math.h>

typedef __attribute__((ext_vector_type(8))) short bf16x8;
typedef __attribute__((ext_vector_type(16))) float f32x16;

#define B_ 2
#define L_ 2048
#define S_ 2048
#define H_ 16
#define E_ 64
#define D_ 64

#define EXP2(x) exp2f(x)

__device__ __forceinline__ unsigned pkbf(float a, float b) {
  __hip_bfloat162 hh = __float22bfloat162_rn(float2{a, b});
  return *(unsigned*)&hh;
}

// D-frag row for mfma_f32_32x32x16: row = (r&3) + 8*(r>>2) + 4*hi5
__device__ __forceinline__ int crow(int r, int hi5) {
  return (r & 3) + ((r >> 2) << 3) + (hi5 << 2);
}

__device__ __forceinline__ void stage_tile(
    const float* __restrict__ Kp, const float* __restrict__ Vp,
    char* lk, char* lv, int bS, int kv0, int h,
    int krow, int ksg, int vd, int kg, int kswz, int vswz) {
  // K: 64 kv x 64 e f32 -> bf16 rows of 128B, XOR-swizzled. thread: 16 e.
  const float* gk = Kp + ((size_t)(bS + kv0 + krow) * H_ + h) * E_ + ksg * 16;
  float4 a0 = ((const float4*)gk)[0];
  float4 a1 = ((const float4*)gk)[1];
  float4 a2 = ((const float4*)gk)[2];
  float4 a3 = ((const float4*)gk)[3];
  uint4 u0{pkbf(a0.x, a0.y), pkbf(a0.z, a0.w), pkbf(a1.x, a1.y), pkbf(a1.z, a1.w)};
  uint4 u1{pkbf(a2.x, a2.y), pkbf(a2.z, a2.w), pkbf(a3.x, a3.y), pkbf(a3.z, a3.w)};
  *(uint4*)(lk + ((krow * 128 + ksg * 32) ^ kswz)) = u0;
  *(uint4*)(lk + ((krow * 128 + ksg * 32 + 16) ^ kswz)) = u1;
  // V^T: row d holds 64 kv; thread: 16 kv of one d (coalesced across lanes).
  const float* gv = Vp + ((size_t)(bS + kv0 + kg * 16) * H_ + h) * D_ + vd;
  float v0 = gv[(size_t)0 * (H_ * D_)],  v1 = gv[(size_t)1 * (H_ * D_)];
  float v2 = gv[(size_t)2 * (H_ * D_)],  v3 = gv[(size_t)3 * (H_ * D_)];
  float v4 = gv[(size_t)4 * (H_ * D_)],  v5 = gv[(size_t)5 * (H_ * D_)];
  float v6 = gv[(size_t)6 * (H_ * D_)],  v7 = gv[(size_t)7 * (H_ * D_)];
  float v8 = gv[(size_t)8 * (H_ * D_)],  v9 = gv[(size_t)9 * (H_ * D_)];
  float va = gv[(size_t)10 * (H_ * D_)], vb = gv[(size_t)11 * (H_ * D_)];
  float vc = gv[(size_t)12 * (H_ * D_)], vdd = gv[(size_t)13 * (H_ * D_)];
  float ve = gv[(size_t)14 * (H_ * D_)], vf = gv[(size_t)15 * (H_ * D_)];
  uint4 w0{pkbf(v0, v1), pkbf(v2, v3), pkbf(v4, v5), pkbf(v6, v7)};
  uint4 w1{pkbf(v8, v9), pkbf(va, vb), pkbf(vc, vdd), pkbf(ve, vf)};
  *(uint4*)(lv + ((vd * 128 + kg * 32) ^ vswz)) = w0;
  *(uint4*)(lv + ((vd * 128 + kg * 32 + 16) ^ vswz)) = w1;
}

__global__ __launch_bounds__(256, 4)
void fa_fwd7(const float* __restrict__ Qp, const float* __restrict__ Kp,
             const float* __restrict__ Vp, float* __restrict__ Op) {
  // 2 buffers x 16KB (K 8KB | V^T 8KB) = 32KB -> 4 blocks/CU
  __shared__ uint4 sbuf[2][1024];

  const int tid  = threadIdx.x;
  const int lane = tid & 63;
  const int w    = tid >> 6;      // 4 waves
  const int sub  = w & 1;         // q-subtile (32 rows)
  const int half = w >> 1;        // kv half of each 64-tile
  const int l31  = lane & 31;
  const int hi5  = lane >> 5;

  // mapping: xcd-local heads (L2 locality); any stride-256 co-resident
  // 4-set has constant tile-sum (66) for balance under breadth-first fill.
  const int Bx   = blockIdx.x;
  const int xcd  = Bx & 7;
  const int rr_  = Bx >> 3;
  const int bh_l = rr_ & 3;
  const int g    = rr_ >> 2;                 // 0..31
  const int qp   = ((g & 7) << 2) | (g >> 3);
  const int p    = (qp & 1) ? 31 - (qp >> 1) : (qp >> 1);  // 64-row q-block id
  const int bh   = xcd * 4 + bh_l;
  const int b    = bh >> 4, h = bh & 15;
  const int q0   = p << 6;
  const int qw   = q0 + sub * 32;            // this wave's 32 q-rows
  const int nt   = p + 1;                    // kv tiles of 64
  const int bS   = b * S_;

  const float cs = 0.125f * 1.44269504088896f;  // 1/sqrt(E) * log2(e)

  // staging coords (256 threads, one 64-kv tile per round)
  const int krow = tid >> 2, ksg = tid & 3;   // K: 64 rows x 4 segs(16e)
  const int vd   = tid & 63, kg  = tid >> 6;  // V: 64 d x 4 kv-groups(16)
  const int kswz = (krow & 7) << 4;
  const int vswz = (vd & 7) << 4;

  // ---- Q fragments (B-operand of swapped QK^T), pre-scaled ----
  bf16x8 qf[4];
  {
    const int qg = qw + l31;
    const float* gq = Qp + ((size_t)(b * L_ + qg) * H_ + h) * E_ + hi5 * 8;
    #pragma unroll
    for (int ec = 0; ec < 4; ++ec) {
      float4 a = *(const float4*)(gq + ec * 16);
      float4 c = *(const float4*)(gq + ec * 16 + 4);
      uint4 u;
      u.x = pkbf(a.x * cs, a.y * cs);
      u.y = pkbf(a.z * cs, a.w * cs);
      u.z = pkbf(c.x * cs, c.y * cs);
      u.w = pkbf(c.z * cs, c.w * cs);
      qf[ec] = *(bf16x8*)&u;
    }
  }

  f32x16 acc[2];
  #pragma unroll
  for (int dt = 0; dt < 2; ++dt)
    #pragma unroll
    for (int r = 0; r < 16; ++r) acc[dt][r] = 0.f;

  float mrun = -INFINITY;
  float lsum = 0.f;

  // prologue: stage tile 0 into buf 0
  stage_tile(Kp, Vp, (char*)&sbuf[0][0], (char*)&sbuf[0][0] + 8192,
             bS, 0, h, krow, ksg, vd, kg, kswz, vswz);
  __syncthreads();

  int cur = 0;
  for (int t = 0; t < nt; ++t, cur ^= 1) {
    if (t + 1 < nt)
      stage_tile(Kp, Vp, (char*)&sbuf[cur ^ 1][0], (char*)&sbuf[cur ^ 1][0] + 8192,
                 bS, (t + 1) * 64, h, krow, ksg, vd, kg, kswz, vswz);

    const int kvh = t * 64 + half * 32;   // this wave's 32-kv slice
    if (kvh <= qw + 31) {
      char* lk = (char*)&sbuf[cur][0];
      char* lv = lk + 8192;

      // swapped QK^T: stt = S^T[kv slice][q]
      f32x16 stt;
      #pragma unroll
      for (int r = 0; r < 16; ++r) stt[r] = 0.f;
      {
        const int row = half * 32 + l31;
        const int sw = (row & 7) << 4;
        __builtin_amdgcn_s_setprio(1);
        #pragma unroll
        for (int ec = 0; ec < 4; ++ec) {
          bf16x8 kf = *(bf16x8*)(lk + ((row * 128 + ec * 32 + hi5 * 16) ^ sw));
          stt = __builtin_amdgcn_mfma_f32_32x32x16_bf16(kf, qf[ec], stt, 0, 0, 0);
        }
        __builtin_amdgcn_s_setprio(0);
      }

      if (kvh + 31 > qw) {   // diagonal: causal mask
        const int qg = qw + l31;
        #pragma unroll
        for (int r = 0; r < 16; ++r)
          if (kvh + crow(r, hi5) > qg) stt[r] = -1e30f;
      }

      // online softmax, defer-max (THR=8 in log2 domain)
      float pm = stt[0];
      #pragma unroll
      for (int r = 1; r < 16; ++r) pm = fmaxf(pm, stt[r]);
      pm = fmaxf(pm, __shfl_xor(pm, 32));

      if (__any(pm > mrun + 8.f)) {
        const float mn = fmaxf(mrun, pm);
        const float f = EXP2(mrun - mn);   // exp2(-inf)=0 first time
        mrun = mn;
        lsum *= f;
        #pragma unroll
        for (int r = 0; r < 16; ++r) {
          const float fr = __shfl(f, crow(r, hi5));
          acc[0][r] *= fr;
          acc[1][r] *= fr;
        }
      }
      {
        float ps = 0.f;
        #pragma unroll
        for (int r = 0; r < 16; ++r) {
          stt[r] = EXP2(stt[r] - mrun);
          ps += stt[r];
        }
        ps += __shfl_xor(ps, 32);
        lsum += ps;
      }

      // P -> PA fragments (pack pairs + lane^32 exchange)
      uint4 pa[2];
      {
        unsigned Dw[8];
        #pragma unroll
        for (int j = 0; j < 8; ++j)
          Dw[j] = pkbf(stt[2 * j], stt[2 * j + 1]);
        unsigned y0 = __shfl_xor((int)(hi5 ? Dw[0] : Dw[2]), 32);
        unsigned y1 = __shfl_xor((int)(hi5 ? Dw[1] : Dw[3]), 32);
        unsigned y2 = __shfl_xor((int)(hi5 ? Dw[4] : Dw[6]), 32);
        unsigned y3 = __shfl_xor((int)(hi5 ? Dw[5] : Dw[7]), 32);
        if (hi5) {
          pa[0] = uint4{y0, y1, Dw[2], Dw[3]};
          pa[1] = uint4{y2, y3, Dw[6], Dw[7]};
        } else {
          pa[0] = uint4{Dw[0], Dw[1], y0, y1};
          pa[1] = uint4{Dw[4], Dw[5], y2, y3};
        }
      }

      // PV: acc[dt] += P(32q x 16kv) . V(16kv x 32d), slots of my half
      __builtin_amdgcn_s_setprio(1);
      #pragma unroll
      for (int j = 0; j < 2; ++j) {
        #pragma unroll
        for (int dt = 0; dt < 2; ++dt) {
          const int row = dt * 32 + l31;
          bf16x8 vf = *(bf16x8*)(lv + ((row * 128 + (half * 2 + j) * 32 + hi5 * 16)
                                       ^ ((row & 7) << 4)));
          acc[dt] = __builtin_amdgcn_mfma_f32_32x32x16_bf16(*(bf16x8*)&pa[j], vf, acc[dt], 0, 0, 0);
        }
      }
      __builtin_amdgcn_s_setprio(0);
    }
    __syncthreads();
  }

  // ---- merge kv-half partials (waves 2,3 -> waves 0,1) + epilogue ----
  char* mb = (char*)&sbuf[0][0];
  const int mswz = (lane & 7) << 4;
  if (half) {
    char* pa_ = mb + sub * 8192 + lane * 128;
    #pragma unroll
    for (int j = 0; j < 4; ++j) {
      *(uint4*)(pa_ + ((j * 16) ^ mswz))      = ((uint4*)&acc[0])[j];
      *(uint4*)(pa_ + ((64 + j * 16) ^ mswz)) = ((uint4*)&acc[1])[j];
    }
    *(float2*)(mb + 16384 + (sub * 64 + lane) * 8) = float2{mrun, lsum};
  }
  __syncthreads();
  if (!half) {
    char* pa_ = mb + sub * 8192 + lane * 128;
    f32x16 a1[2];
    #pragma unroll
    for (int j = 0; j < 4; ++j) {
      ((uint4*)&a1[0])[j] = *(uint4*)(pa_ + ((j * 16) ^ mswz));
      ((uint4*)&a1[1])[j] = *(uint4*)(pa_ + ((64 + j * 16) ^ mswz));
    }
    float2 ml = *(float2*)(mb + 16384 + (sub * 64 + lane) * 8);
    const float m1 = ml.x, l1 = ml.y;
    const float mm = fmaxf(mrun, m1);
    const float f0 = EXP2(mrun - mm);
    const float f1 = EXP2(m1 - mm);    // exp2(-inf)=0 covers empty half
    const float inv = 1.f / (lsum * f0 + l1 * f1);
    const float g0 = f0 * inv, g1 = f1 * inv;
    #pragma unroll
    for (int r = 0; r < 16; ++r) {
      const int cr = crow(r, hi5);
      const float w0 = __shfl(g0, cr);
      const float w1 = __shfl(g1, cr);
      const int qg = qw + cr;
      float* go = Op + ((size_t)(b * L_ + qg) * H_ + h) * D_ + l31;
      go[0]  = acc[0][r] * w0 + a1[0][r] * w1;
      go[32] = acc[1][r] * w0 + a1[1][r] * w1;
    }
  }
}

extern "C" void kernel_launch(void* const* d_in, const int* in_sizes, int n_in,
                              void* d_out, int out_size, void* d_ws, size_t ws_size,
                              hipStream_t stream) {
  (void)in_sizes; (void)n_in; (void)d_ws; (void)ws_size; (void)out_size;
  const float* Q = (const float*)d_in[0];
  const float* K = (const float*)d_in[1];
  const float* V = (const float*)d_in[2];
  float* O = (float*)d_out;
  fa_fwd7<<<dim3(1024), dim3(256), 0, stream>>>(Q, K, V, O);
}